// Round 1
// baseline (8005.260 us; speedup 1.0000x reference)
//
#include <hip/hip_runtime.h>
#include <cstdint>
#include <cstddef>

#define N_NODES   100000
#define N_EDGES   3200000
#define IN_FEATS  256
#define N_HIDDEN  128
#define OUT_FEATS 40

// ---------------------------------------------------------------------------
// GEMM0: h0 = x @ W0   [N,256] x [256,128] -> [N,128]
// 8 rows per block, 256 threads; thread (r = tid/32, cols c..c+3 = (tid%32)*4).
// x rows staged in LDS (broadcast reads); W0 read as float4, L1/L2 resident.
// ---------------------------------------------------------------------------
__global__ __launch_bounds__(256) void gemm0_kernel(
    const float* __restrict__ x, const float* __restrict__ W0,
    float* __restrict__ h0) {
  __shared__ float xs[8 * IN_FEATS];
  const int row0 = blockIdx.x * 8;
  const int tid  = threadIdx.x;

  const float* xbase = x + (size_t)row0 * IN_FEATS;
#pragma unroll
  for (int i = tid; i < 8 * IN_FEATS; i += 256) xs[i] = xbase[i];
  __syncthreads();

  const int r = tid >> 5;
  const int c = (tid & 31) * 4;
  const float* xr = xs + r * IN_FEATS;

  float4 acc = make_float4(0.f, 0.f, 0.f, 0.f);
#pragma unroll 4
  for (int k = 0; k < IN_FEATS; ++k) {
    const float4 w = *(const float4*)(W0 + (size_t)k * N_HIDDEN + c);
    const float xv = xr[k];
    acc.x = fmaf(xv, w.x, acc.x);
    acc.y = fmaf(xv, w.y, acc.y);
    acc.z = fmaf(xv, w.z, acc.z);
    acc.w = fmaf(xv, w.w, acc.w);
  }
  *(float4*)(h0 + (size_t)(row0 + r) * N_HIDDEN + c) = acc;
}

// ---------------------------------------------------------------------------
// Scatter0: agg0[dst[e]] += h0[src[e]] * ew[e]  over 128 feats.
// One thread per (edge, 4-feat chunk): 32 chunks/edge.
// ---------------------------------------------------------------------------
__global__ __launch_bounds__(256) void scatter0_kernel(
    const float* __restrict__ h0, const float* __restrict__ ew,
    const int* __restrict__ src, const int* __restrict__ dst,
    float* __restrict__ agg0) {
  const int gid = blockIdx.x * 256 + threadIdx.x;   // < E*32 = 102.4M
  const int e     = gid >> 5;
  const int chunk = (gid & 31) * 4;
  if (e >= N_EDGES) return;
  const int s = src[e];
  const int d = dst[e];
  const float w = ew[e];
  const float4 v = *(const float4*)(h0 + (size_t)s * N_HIDDEN + chunk);
  float* o = agg0 + (size_t)d * N_HIDDEN + chunk;
  unsafeAtomicAdd(o + 0, v.x * w);
  unsafeAtomicAdd(o + 1, v.y * w);
  unsafeAtomicAdd(o + 2, v.z * w);
  unsafeAtomicAdd(o + 3, v.w * w);
}

// ---------------------------------------------------------------------------
// GEMM1: h1 = relu(agg0 + b0) @ W1   [N,128] x [128,40] -> [N,40]
// 4 rows per block (one wave each); lanes 0..39 compute one column.
// bias+ReLU fused into the LDS staging of the h rows.
// ---------------------------------------------------------------------------
__global__ __launch_bounds__(256) void gemm1_kernel(
    const float* __restrict__ agg0, const float* __restrict__ b0,
    const float* __restrict__ W1, float* __restrict__ h1) {
  __shared__ float hs[4 * N_HIDDEN];
  const int row0 = blockIdx.x * 4;
  const int tid  = threadIdx.x;

  for (int i = tid; i < 4 * N_HIDDEN; i += 256) {
    const int rr = i >> 7, ff = i & 127;
    const float v = agg0[(size_t)(row0 + rr) * N_HIDDEN + ff] + b0[ff];
    hs[i] = v > 0.f ? v : 0.f;
  }
  __syncthreads();

  const int r = tid >> 6;
  const int c = tid & 63;
  if (c < OUT_FEATS) {
    const float* hr = hs + r * N_HIDDEN;
    float acc = 0.f;
#pragma unroll 4
    for (int k = 0; k < N_HIDDEN; ++k)
      acc = fmaf(hr[k], W1[k * OUT_FEATS + c], acc);
    h1[(size_t)(row0 + r) * OUT_FEATS + c] = acc;
  }
}

// ---------------------------------------------------------------------------
// Scatter1: agg1[dst[e]] += h1[src[e]] * ew[e]  over 40 feats.
// One thread per (edge, 4-feat chunk): 10 chunks/edge.
// ---------------------------------------------------------------------------
__global__ __launch_bounds__(256) void scatter1_kernel(
    const float* __restrict__ h1, const float* __restrict__ ew,
    const int* __restrict__ src, const int* __restrict__ dst,
    float* __restrict__ agg1) {
  const int gid = blockIdx.x * 256 + threadIdx.x;   // < E*10 = 32M
  const int e = gid / 10;
  if (e >= N_EDGES) return;
  const int chunk = (gid - e * 10) * 4;
  const int s = src[e];
  const int d = dst[e];
  const float w = ew[e];
  const float4 v = *(const float4*)(h1 + (size_t)s * OUT_FEATS + chunk);
  float* o = agg1 + (size_t)d * OUT_FEATS + chunk;
  unsafeAtomicAdd(o + 0, v.x * w);
  unsafeAtomicAdd(o + 1, v.y * w);
  unsafeAtomicAdd(o + 2, v.z * w);
  unsafeAtomicAdd(o + 3, v.w * w);
}

// ---------------------------------------------------------------------------
// Epilogue: out = log_softmax(agg1 + b1, axis=1). One wave per row (40 cols).
// ---------------------------------------------------------------------------
__global__ __launch_bounds__(256) void lsm_kernel(
    const float* __restrict__ agg1, const float* __restrict__ b1,
    float* __restrict__ out) {
  const int lane = threadIdx.x & 63;
  const int row  = blockIdx.x * 4 + (threadIdx.x >> 6);
  if (row >= N_NODES) return;

  float v = -INFINITY;
  if (lane < OUT_FEATS) v = agg1[(size_t)row * OUT_FEATS + lane] + b1[lane];

  float m = v;
#pragma unroll
  for (int off = 32; off > 0; off >>= 1) m = fmaxf(m, __shfl_xor(m, off));

  float s = (lane < OUT_FEATS) ? expf(v - m) : 0.f;
#pragma unroll
  for (int off = 32; off > 0; off >>= 1) s += __shfl_xor(s, off);

  if (lane < OUT_FEATS)
    out[(size_t)row * OUT_FEATS + lane] = v - m - logf(s);
}

// ---------------------------------------------------------------------------
extern "C" void kernel_launch(void* const* d_in, const int* in_sizes, int n_in,
                              void* d_out, int out_size, void* d_ws, size_t ws_size,
                              hipStream_t stream) {
  const float* x  = (const float*)d_in[0];
  const float* W0 = (const float*)d_in[1];
  const float* b0 = (const float*)d_in[2];
  const float* W1 = (const float*)d_in[3];
  const float* b1 = (const float*)d_in[4];
  const float* ew = (const float*)d_in[5];
  const int*   src = (const int*)d_in[6];
  const int*   dst = (const int*)d_in[7];
  float* out = (float*)d_out;

  // Workspace layout (peak 102.4 MB):
  //   [0, 51.2MB)        h0  (N*128 f32)  — dead after scatter0
  //   [0, 16MB)          h1  (N*40 f32)   — reuses h0 region after gemm1
  //   [16MB, 32MB)       agg1 (N*40 f32)  — reuses h0 region; memset AFTER gemm1
  //   [51.2MB, 102.4MB)  agg0 (N*128 f32)
  char* ws = (char*)d_ws;
  const size_t h0_bytes   = (size_t)N_NODES * N_HIDDEN * sizeof(float);   // 51.2 MB
  const size_t h1_bytes   = (size_t)N_NODES * OUT_FEATS * sizeof(float);  // 16 MB
  float* h0   = (float*)ws;
  float* h1   = (float*)ws;
  float* agg1 = (float*)(ws + h1_bytes);
  float* agg0 = (float*)(ws + h0_bytes);

  hipMemsetAsync(agg0, 0, h0_bytes, stream);

  gemm0_kernel<<<N_NODES / 8, 256, 0, stream>>>(x, W0, h0);

  scatter0_kernel<<<(N_EDGES * 32) / 256, 256, 0, stream>>>(h0, ew, src, dst, agg0);

  gemm1_kernel<<<N_NODES / 4, 256, 0, stream>>>(agg0, b0, W1, h1);

  // agg1 overlaps the (now dead) h0 region; zero it only after gemm1 ran.
  hipMemsetAsync(agg1, 0, h1_bytes, stream);

  scatter1_kernel<<<(N_EDGES * 10 + 255) / 256, 256, 0, stream>>>(h1, ew, src, dst, agg1);

  lsm_kernel<<<N_NODES / 4, 256, 0, stream>>>(agg1, b1, out);
}

// Round 2
// 1795.581 us; speedup vs baseline: 4.4583x; 4.4583x over previous
//
#include <hip/hip_runtime.h>
#include <cstdint>
#include <cstddef>

#define N_NODES   100000
#define N_EDGES   3200000
#define IN_FEATS  256
#define N_HIDDEN  128
#define OUT_FEATS 40

// ---------------------------------------------------------------------------
// GEMM0: h0 = x @ W0   [N,256] x [256,128] -> [N,128]
// 8 rows per block, 256 threads; thread (r = tid/32, cols c..c+3 = (tid%32)*4).
// ---------------------------------------------------------------------------
__global__ __launch_bounds__(256) void gemm0_kernel(
    const float* __restrict__ x, const float* __restrict__ W0,
    float* __restrict__ h0) {
  __shared__ float xs[8 * IN_FEATS];
  const int row0 = blockIdx.x * 8;
  const int tid  = threadIdx.x;

  const float* xbase = x + (size_t)row0 * IN_FEATS;
#pragma unroll
  for (int i = tid; i < 8 * IN_FEATS; i += 256) xs[i] = xbase[i];
  __syncthreads();

  const int r = tid >> 5;
  const int c = (tid & 31) * 4;
  const float* xr = xs + r * IN_FEATS;

  float4 acc = make_float4(0.f, 0.f, 0.f, 0.f);
#pragma unroll 4
  for (int k = 0; k < IN_FEATS; ++k) {
    const float4 w = *(const float4*)(W0 + (size_t)k * N_HIDDEN + c);
    const float xv = xr[k];
    acc.x = fmaf(xv, w.x, acc.x);
    acc.y = fmaf(xv, w.y, acc.y);
    acc.z = fmaf(xv, w.z, acc.z);
    acc.w = fmaf(xv, w.w, acc.w);
  }
  *(float4*)(h0 + (size_t)(row0 + r) * N_HIDDEN + c) = acc;
}

// ---------------------------------------------------------------------------
// CSR build step 1: histogram of dst.  3.2M int atomics (cheap vs 410M f32).
// ---------------------------------------------------------------------------
__global__ __launch_bounds__(256) void hist_kernel(
    const int* __restrict__ dst, int* __restrict__ deg) {
  const int e = blockIdx.x * 256 + threadIdx.x;
  if (e < N_EDGES) atomicAdd(&deg[dst[e]], 1);
}

// ---------------------------------------------------------------------------
// CSR build step 2: exclusive scan of deg -> offsets (and cursor copy).
// Single block of 1024 threads; each thread serially handles a 98-elem chunk,
// Hillis-Steele scan of the 1024 partials in LDS, then chunk write-back.
// ---------------------------------------------------------------------------
#define SCAN_T 1024
__global__ __launch_bounds__(SCAN_T) void scan_kernel(
    const int* __restrict__ deg, int* __restrict__ offsets,
    int* __restrict__ cursor) {
  __shared__ int partials[SCAN_T];
  const int t = threadIdx.x;
  const int chunk = (N_NODES + SCAN_T - 1) / SCAN_T;   // 98
  const int lo = t * chunk;
  const int hi = min(lo + chunk, N_NODES);

  int sum = 0;
  for (int i = lo; i < hi; ++i) sum += deg[i];
  partials[t] = sum;
  __syncthreads();

  for (int off = 1; off < SCAN_T; off <<= 1) {
    int v = (t >= off) ? partials[t - off] : 0;
    __syncthreads();
    partials[t] += v;
    __syncthreads();
  }

  int run = (t > 0) ? partials[t - 1] : 0;   // exclusive base
  for (int i = lo; i < hi; ++i) {
    const int d = deg[i];
    offsets[i] = run;
    cursor[i]  = run;
    run += d;
  }
  if (t == SCAN_T - 1) offsets[N_NODES] = run;   // == N_EDGES
}

// ---------------------------------------------------------------------------
// CSR build step 3: place (src, weight) packed 8B into dst-sorted order.
// ---------------------------------------------------------------------------
__global__ __launch_bounds__(256) void place_kernel(
    const int* __restrict__ src, const int* __restrict__ dst,
    const float* __restrict__ ew, int* __restrict__ cursor,
    int2* __restrict__ srcw) {
  const int e = blockIdx.x * 256 + threadIdx.x;
  if (e < N_EDGES) {
    const int p = atomicAdd(&cursor[dst[e]], 1);
    srcw[p] = make_int2(src[e], __float_as_int(ew[e]));
  }
}

// ---------------------------------------------------------------------------
// Fused gather0 + bias + ReLU + GEMM1: h1 = relu(A@h0 + b0) @ W1.
// One wave per node. Phase 1: lane holds feats {2l, 2l+1}; accumulate over
// incoming edges (float2 gather of h0 rows — 512B/wave coalesced, L3-served).
// Phase 2: LDS round-trip, lanes 0..39 dot the 128-vec with W1 columns.
// ---------------------------------------------------------------------------
__global__ __launch_bounds__(256) void gather0_gemm1_kernel(
    const float* __restrict__ h0, const int2* __restrict__ srcw,
    const int* __restrict__ offsets, const float* __restrict__ b0,
    const float* __restrict__ W1, float* __restrict__ h1) {
  __shared__ float hs[4][N_HIDDEN];
  const int wave = threadIdx.x >> 6;
  const int lane = threadIdx.x & 63;
  const int node = blockIdx.x * 4 + wave;   // grid 25000 -> exact

  const int beg = offsets[node];
  const int end = offsets[node + 1];
  const int f   = lane * 2;

  float2 acc = make_float2(0.f, 0.f);
  for (int j = beg; j < end; ++j) {
    const int2 sw = srcw[j];
    const float w = __int_as_float(sw.y);
    const float2 v = *(const float2*)(h0 + (size_t)sw.x * N_HIDDEN + f);
    acc.x = fmaf(v.x, w, acc.x);
    acc.y = fmaf(v.y, w, acc.y);
  }
  const float a0 = acc.x + b0[f];
  const float a1 = acc.y + b0[f + 1];
  hs[wave][f]     = a0 > 0.f ? a0 : 0.f;
  hs[wave][f + 1] = a1 > 0.f ? a1 : 0.f;
  __syncthreads();

  if (lane < OUT_FEATS) {
    float o = 0.f;
#pragma unroll 8
    for (int k = 0; k < N_HIDDEN; ++k)
      o = fmaf(hs[wave][k], W1[k * OUT_FEATS + lane], o);  // LDS broadcast, free
    h1[(size_t)node * OUT_FEATS + lane] = o;
  }
}

// ---------------------------------------------------------------------------
// Fused gather1 + bias + log_softmax. One wave per node; lanes 0..39 own one
// output feature each; shuffle-reduce max and sum across the wave.
// ---------------------------------------------------------------------------
__global__ __launch_bounds__(256) void gather1_lsm_kernel(
    const float* __restrict__ h1, const int2* __restrict__ srcw,
    const int* __restrict__ offsets, const float* __restrict__ b1,
    float* __restrict__ out) {
  const int wave = threadIdx.x >> 6;
  const int lane = threadIdx.x & 63;
  const int node = blockIdx.x * 4 + wave;

  const int beg = offsets[node];
  const int end = offsets[node + 1];

  float acc;
  if (lane < OUT_FEATS) {
    acc = 0.f;
    for (int j = beg; j < end; ++j) {
      const int2 sw = srcw[j];
      acc = fmaf(h1[(size_t)sw.x * OUT_FEATS + lane], __int_as_float(sw.y), acc);
    }
    acc += b1[lane];
  } else {
    acc = -INFINITY;
  }

  float m = acc;
#pragma unroll
  for (int off = 32; off > 0; off >>= 1) m = fmaxf(m, __shfl_xor(m, off));

  float s = (lane < OUT_FEATS) ? expf(acc - m) : 0.f;
#pragma unroll
  for (int off = 32; off > 0; off >>= 1) s += __shfl_xor(s, off);

  if (lane < OUT_FEATS)
    out[(size_t)node * OUT_FEATS + lane] = acc - m - logf(s);
}

// ---------------------------------------------------------------------------
extern "C" void kernel_launch(void* const* d_in, const int* in_sizes, int n_in,
                              void* d_out, int out_size, void* d_ws, size_t ws_size,
                              hipStream_t stream) {
  const float* x   = (const float*)d_in[0];
  const float* W0  = (const float*)d_in[1];
  const float* b0  = (const float*)d_in[2];
  const float* W1  = (const float*)d_in[3];
  const float* b1  = (const float*)d_in[4];
  const float* ew  = (const float*)d_in[5];
  const int*   src = (const int*)d_in[6];
  const int*   dst = (const int*)d_in[7];
  float* out = (float*)d_out;

  // Workspace layout, peak 94.0 MB (<= 102.4 MB proven available in R1):
  //   h0      [0,          51,200,000)   N*128 f32
  //   srcw    [51,200,000, 76,800,000)   E int2 (src, weight-bits), dst-sorted
  //   offsets [76,800,000, 77,200,064)   N+1 int
  //   deg     [77,200,064, 77,600,064)   N int
  //   cursor  [77,600,064, 78,000,064)   N int
  //   h1      [78,000,064, 94,000,064)   N*40 f32
  char* ws = (char*)d_ws;
  float* h0      = (float*)(ws);
  int2*  srcw    = (int2*)(ws + 51200000);
  int*   offsets = (int*)(ws + 76800000);
  int*   deg     = (int*)(ws + 77200064);
  int*   cursor  = (int*)(ws + 77600064);
  float* h1      = (float*)(ws + 78000064);

  // CSR build (re-derived every call; ws is re-poisoned by the harness).
  hipMemsetAsync(deg, 0, (size_t)N_NODES * sizeof(int), stream);
  hist_kernel<<<N_EDGES / 256, 256, 0, stream>>>(dst, deg);
  scan_kernel<<<1, SCAN_T, 0, stream>>>(deg, offsets, cursor);
  place_kernel<<<N_EDGES / 256, 256, 0, stream>>>(src, dst, ew, cursor, srcw);

  // Dense transform + fused gather stages.
  gemm0_kernel<<<N_NODES / 8, 256, 0, stream>>>(x, W0, h0);
  gather0_gemm1_kernel<<<N_NODES / 4, 256, 0, stream>>>(h0, srcw, offsets, b0, W1, h1);
  gather1_lsm_kernel<<<N_NODES / 4, 256, 0, stream>>>(h1, srcw, offsets, b1, out);
}

// Round 3
// 1208.308 us; speedup vs baseline: 6.6252x; 1.4860x over previous
//
#include <hip/hip_runtime.h>
#include <hip/hip_bf16.h>
#include <cstdint>
#include <cstddef>

#define N_NODES   100000
#define N_EDGES   3200000
#define IN_FEATS  256
#define N_HIDDEN  128
#define OUT_FEATS 40

// ---------------------------------------------------------------------------
// GEMM0: h0 = bf16(x @ W0)   [N,256]x[256,128] -> [N,128] bf16
// Tile: 32 rows x 128 cols per block (256 thr). Wave w owns rows 8w..8w+7;
// lane owns 2 cols (c=2*lane) x 8 rows -> acc[8][2], 16 independent chains.
// x tile staged TRANSPOSED in LDS: xsT[k][row], pad 36 so &xsT[k][8w] is
// 16B-aligned -> two ds_read_b128 at a wave-uniform address (broadcast).
// ---------------------------------------------------------------------------
__global__ __launch_bounds__(256) void gemm0_kernel(
    const float* __restrict__ x, const float* __restrict__ W0,
    unsigned int* __restrict__ h0b2 /* bf16x2 words, [N][64] */) {
  __shared__ float xsT[IN_FEATS][36];   // 36*4=144B rows: 16B-aligned ∀k
  const int tid  = threadIdx.x;
  const int row0 = blockIdx.x * 32;

  // Stage x tile transposed. Mapping row=i&31 keeps LDS writes conflict-free
  // (bank = (4k+row)%32 covers all 32 banks across a wave); global reads are
  // 16B-granular with stride 1KB — L1/L2 absorb (each line hit by 4 threads).
  for (int i = tid; i < 32 * 64; i += 256) {
    const int k4  = i >> 5;       // 0..63
    const int row = i & 31;       // 0..31
    const float4 v = *(const float4*)(x + (size_t)(row0 + row) * IN_FEATS + k4 * 4);
    xsT[k4 * 4 + 0][row] = v.x;
    xsT[k4 * 4 + 1][row] = v.y;
    xsT[k4 * 4 + 2][row] = v.z;
    xsT[k4 * 4 + 3][row] = v.w;
  }
  __syncthreads();

  const int wave = tid >> 6;
  const int lane = tid & 63;
  const int r0   = wave * 8;
  const int c    = lane * 2;

  float acc[8][2];
#pragma unroll
  for (int r = 0; r < 8; ++r) { acc[r][0] = 0.f; acc[r][1] = 0.f; }

#pragma unroll 4
  for (int k = 0; k < IN_FEATS; ++k) {
    const float2 w = *(const float2*)(W0 + (size_t)k * N_HIDDEN + c);
    const float4 a0 = *(const float4*)&xsT[k][r0];
    const float4 a1 = *(const float4*)&xsT[k][r0 + 4];
    acc[0][0] = fmaf(a0.x, w.x, acc[0][0]); acc[0][1] = fmaf(a0.x, w.y, acc[0][1]);
    acc[1][0] = fmaf(a0.y, w.x, acc[1][0]); acc[1][1] = fmaf(a0.y, w.y, acc[1][1]);
    acc[2][0] = fmaf(a0.z, w.x, acc[2][0]); acc[2][1] = fmaf(a0.z, w.y, acc[2][1]);
    acc[3][0] = fmaf(a0.w, w.x, acc[3][0]); acc[3][1] = fmaf(a0.w, w.y, acc[3][1]);
    acc[4][0] = fmaf(a1.x, w.x, acc[4][0]); acc[4][1] = fmaf(a1.x, w.y, acc[4][1]);
    acc[5][0] = fmaf(a1.y, w.x, acc[5][0]); acc[5][1] = fmaf(a1.y, w.y, acc[5][1]);
    acc[6][0] = fmaf(a1.z, w.x, acc[6][0]); acc[6][1] = fmaf(a1.z, w.y, acc[6][1]);
    acc[7][0] = fmaf(a1.w, w.x, acc[7][0]); acc[7][1] = fmaf(a1.w, w.y, acc[7][1]);
  }

#pragma unroll
  for (int r = 0; r < 8; ++r) {
    __hip_bfloat162 p;
    p.x = __float2bfloat16(acc[r][0]);
    p.y = __float2bfloat16(acc[r][1]);
    h0b2[(size_t)(row0 + r0 + r) * 64 + lane] = *(unsigned int*)&p;
  }
}

// ---------------------------------------------------------------------------
// CSR build: histogram -> scan -> place (int atomics only).
// ---------------------------------------------------------------------------
__global__ __launch_bounds__(256) void hist_kernel(
    const int* __restrict__ dst, int* __restrict__ deg) {
  const int e = blockIdx.x * 256 + threadIdx.x;
  if (e < N_EDGES) atomicAdd(&deg[dst[e]], 1);
}

#define SCAN_T 1024
__global__ __launch_bounds__(SCAN_T) void scan_kernel(
    const int* __restrict__ deg, int* __restrict__ offsets,
    int* __restrict__ cursor) {
  __shared__ int partials[SCAN_T];
  const int t = threadIdx.x;
  const int chunk = (N_NODES + SCAN_T - 1) / SCAN_T;   // 98
  const int lo = t * chunk;
  const int hi = min(lo + chunk, N_NODES);

  int sum = 0;
  for (int i = lo; i < hi; ++i) sum += deg[i];
  partials[t] = sum;
  __syncthreads();

  for (int off = 1; off < SCAN_T; off <<= 1) {
    int v = (t >= off) ? partials[t - off] : 0;
    __syncthreads();
    partials[t] += v;
    __syncthreads();
  }

  int run = (t > 0) ? partials[t - 1] : 0;
  for (int i = lo; i < hi; ++i) {
    const int d = deg[i];
    offsets[i] = run;
    cursor[i]  = run;
    run += d;
  }
  if (t == SCAN_T - 1) offsets[N_NODES] = run;
}

__global__ __launch_bounds__(256) void place_kernel(
    const int* __restrict__ src, const int* __restrict__ dst,
    const float* __restrict__ ew, int* __restrict__ cursor,
    int2* __restrict__ srcw) {
  const int e = blockIdx.x * 256 + threadIdx.x;
  if (e < N_EDGES) {
    const int p = atomicAdd(&cursor[dst[e]], 1);
    srcw[p] = make_int2(src[e], __float_as_int(ew[e]));
  }
}

// ---------------------------------------------------------------------------
// Fused gather0 + bias + ReLU + GEMM1. h0 is bf16x2 words (4B/lane/edge).
// readfirstlane(beg/end) -> uniform loop -> srcw[j] becomes s_load (K$ path).
// ---------------------------------------------------------------------------
__global__ __launch_bounds__(256) void gather0_gemm1_kernel(
    const unsigned int* __restrict__ h0b2, const int2* __restrict__ srcw,
    const int* __restrict__ offsets, const float* __restrict__ b0,
    const float* __restrict__ W1, float* __restrict__ h1) {
  __shared__ float hs[4][N_HIDDEN];
  const int wave = threadIdx.x >> 6;
  const int lane = threadIdx.x & 63;
  const int node = blockIdx.x * 4 + wave;

  const int beg = __builtin_amdgcn_readfirstlane(offsets[node]);
  const int end = __builtin_amdgcn_readfirstlane(offsets[node + 1]);
  const int f   = lane * 2;

  float ax = 0.f, ay = 0.f;
  int j = beg;
  for (; j + 2 <= end; j += 2) {
    const int2 s0 = srcw[j];
    const int2 s1 = srcw[j + 1];
    const unsigned int u0 = h0b2[(size_t)s0.x * 64 + lane];
    const unsigned int u1 = h0b2[(size_t)s1.x * 64 + lane];
    const float w0 = __int_as_float(s0.y);
    const float w1 = __int_as_float(s1.y);
    ax = fmaf(__uint_as_float(u0 << 16), w0, ax);
    ay = fmaf(__uint_as_float(u0 & 0xFFFF0000u), w0, ay);
    ax = fmaf(__uint_as_float(u1 << 16), w1, ax);
    ay = fmaf(__uint_as_float(u1 & 0xFFFF0000u), w1, ay);
  }
  if (j < end) {
    const int2 s0 = srcw[j];
    const unsigned int u0 = h0b2[(size_t)s0.x * 64 + lane];
    const float w0 = __int_as_float(s0.y);
    ax = fmaf(__uint_as_float(u0 << 16), w0, ax);
    ay = fmaf(__uint_as_float(u0 & 0xFFFF0000u), w0, ay);
  }

  const float v0 = ax + b0[f];
  const float v1 = ay + b0[f + 1];
  hs[wave][f]     = v0 > 0.f ? v0 : 0.f;
  hs[wave][f + 1] = v1 > 0.f ? v1 : 0.f;
  __syncthreads();

  if (lane < OUT_FEATS) {
    float o = 0.f;
#pragma unroll 8
    for (int k = 0; k < N_HIDDEN; ++k)
      o = fmaf(hs[wave][k], W1[k * OUT_FEATS + lane], o);
    h1[(size_t)node * OUT_FEATS + lane] = o;
  }
}

// ---------------------------------------------------------------------------
// Fused gather1 + bias + log_softmax. One wave per node; lanes 0..39 own one
// output feature; shuffle-reduce for max and sum.
// ---------------------------------------------------------------------------
__global__ __launch_bounds__(256) void gather1_lsm_kernel(
    const float* __restrict__ h1, const int2* __restrict__ srcw,
    const int* __restrict__ offsets, const float* __restrict__ b1,
    float* __restrict__ out) {
  const int wave = threadIdx.x >> 6;
  const int lane = threadIdx.x & 63;
  const int node = blockIdx.x * 4 + wave;

  const int beg = __builtin_amdgcn_readfirstlane(offsets[node]);
  const int end = __builtin_amdgcn_readfirstlane(offsets[node + 1]);

  float acc = 0.f;
  if (lane < OUT_FEATS) {
    int j = beg;
    for (; j + 2 <= end; j += 2) {
      const int2 s0 = srcw[j];
      const int2 s1 = srcw[j + 1];
      const float v0 = h1[(size_t)s0.x * OUT_FEATS + lane];
      const float v1 = h1[(size_t)s1.x * OUT_FEATS + lane];
      acc = fmaf(v0, __int_as_float(s0.y), acc);
      acc = fmaf(v1, __int_as_float(s1.y), acc);
    }
    if (j < end) {
      const int2 s0 = srcw[j];
      acc = fmaf(h1[(size_t)s0.x * OUT_FEATS + lane], __int_as_float(s0.y), acc);
    }
    acc += b1[lane];
  } else {
    acc = -INFINITY;
  }

  float m = acc;
#pragma unroll
  for (int off = 32; off > 0; off >>= 1) m = fmaxf(m, __shfl_xor(m, off));

  float s = (lane < OUT_FEATS) ? expf(acc - m) : 0.f;
#pragma unroll
  for (int off = 32; off > 0; off >>= 1) s += __shfl_xor(s, off);

  if (lane < OUT_FEATS)
    out[(size_t)node * OUT_FEATS + lane] = acc - m - logf(s);
}

// ---------------------------------------------------------------------------
extern "C" void kernel_launch(void* const* d_in, const int* in_sizes, int n_in,
                              void* d_out, int out_size, void* d_ws, size_t ws_size,
                              hipStream_t stream) {
  const float* x   = (const float*)d_in[0];
  const float* W0  = (const float*)d_in[1];
  const float* b0  = (const float*)d_in[2];
  const float* W1  = (const float*)d_in[3];
  const float* b1  = (const float*)d_in[4];
  const float* ew  = (const float*)d_in[5];
  const int*   src = (const int*)d_in[6];
  const int*   dst = (const int*)d_in[7];
  float* out = (float*)d_out;

  // Workspace layout, peak ~68.4 MB:
  //   h0b2    [0,          25,600,000)   N*64 uint (bf16x2)
  //   srcw    [25,600,000, 51,200,000)   E int2 (src, weight-bits), dst-sorted
  //   offsets [51,200,000, 51,600,064)   N+1 int
  //   deg     [51,600,064, 52,000,064)   N int
  //   cursor  [52,000,064, 52,400,064)   N int
  //   h1      [52,400,064, 68,400,064)   N*40 f32
  char* ws = (char*)d_ws;
  unsigned int* h0b2 = (unsigned int*)(ws);
  int2*  srcw    = (int2*)(ws + 25600000);
  int*   offsets = (int*)(ws + 51200000);
  int*   deg     = (int*)(ws + 51600064);
  int*   cursor  = (int*)(ws + 52000064);
  float* h1      = (float*)(ws + 52400064);

  hipMemsetAsync(deg, 0, (size_t)N_NODES * sizeof(int), stream);
  hist_kernel<<<N_EDGES / 256, 256, 0, stream>>>(dst, deg);
  scan_kernel<<<1, SCAN_T, 0, stream>>>(deg, offsets, cursor);
  place_kernel<<<N_EDGES / 256, 256, 0, stream>>>(src, dst, ew, cursor, srcw);

  gemm0_kernel<<<N_NODES / 32, 256, 0, stream>>>(x, W0, h0b2);
  gather0_gemm1_kernel<<<N_NODES / 4, 256, 0, stream>>>(h0b2, srcw, offsets, b0, W1, h1);
  gather1_lsm_kernel<<<N_NODES / 4, 256, 0, stream>>>(h1, srcw, offsets, b1, out);
}

// Round 4
// 783.023 us; speedup vs baseline: 10.2235x; 1.5431x over previous
//
#include <hip/hip_runtime.h>
#include <hip/hip_bf16.h>
#include <cstdint>
#include <cstddef>

#define N_NODES   100000
#define N_EDGES   3200000
#define IN_FEATS  256
#define N_HIDDEN  128
#define OUT_FEATS 40

// Bucket partition: bucket = dst >> 9 (512 nodes/bucket)
#define NB        196      // ceil(100000/512); last bucket has 160 nodes
#define EPB       8192     // edges per partition block
#define NBLK      391      // ceil(3.2M/8192)
#define HIST_M    (NB * NBLK)   // 76,636

// ---------------------------------------------------------------------------
// GEMM0: h0 = bf16(x @ W0)  (unchanged from R3: 32x128 tile, acc[8][2]/lane)
// ---------------------------------------------------------------------------
__global__ __launch_bounds__(256) void gemm0_kernel(
    const float* __restrict__ x, const float* __restrict__ W0,
    unsigned int* __restrict__ h0b2 /* bf16x2 words, [N][64] */) {
  __shared__ float xsT[IN_FEATS][36];
  const int tid  = threadIdx.x;
  const int row0 = blockIdx.x * 32;

  for (int i = tid; i < 32 * 64; i += 256) {
    const int k4  = i >> 5;
    const int row = i & 31;
    const float4 v = *(const float4*)(x + (size_t)(row0 + row) * IN_FEATS + k4 * 4);
    xsT[k4 * 4 + 0][row] = v.x;
    xsT[k4 * 4 + 1][row] = v.y;
    xsT[k4 * 4 + 2][row] = v.z;
    xsT[k4 * 4 + 3][row] = v.w;
  }
  __syncthreads();

  const int wave = tid >> 6;
  const int lane = tid & 63;
  const int r0   = wave * 8;
  const int c    = lane * 2;

  float acc[8][2];
#pragma unroll
  for (int r = 0; r < 8; ++r) { acc[r][0] = 0.f; acc[r][1] = 0.f; }

#pragma unroll 4
  for (int k = 0; k < IN_FEATS; ++k) {
    const float2 w = *(const float2*)(W0 + (size_t)k * N_HIDDEN + c);
    const float4 a0 = *(const float4*)&xsT[k][r0];
    const float4 a1 = *(const float4*)&xsT[k][r0 + 4];
    acc[0][0] = fmaf(a0.x, w.x, acc[0][0]); acc[0][1] = fmaf(a0.x, w.y, acc[0][1]);
    acc[1][0] = fmaf(a0.y, w.x, acc[1][0]); acc[1][1] = fmaf(a0.y, w.y, acc[1][1]);
    acc[2][0] = fmaf(a0.z, w.x, acc[2][0]); acc[2][1] = fmaf(a0.z, w.y, acc[2][1]);
    acc[3][0] = fmaf(a0.w, w.x, acc[3][0]); acc[3][1] = fmaf(a0.w, w.y, acc[3][1]);
    acc[4][0] = fmaf(a1.x, w.x, acc[4][0]); acc[4][1] = fmaf(a1.x, w.y, acc[4][1]);
    acc[5][0] = fmaf(a1.y, w.x, acc[5][0]); acc[5][1] = fmaf(a1.y, w.y, acc[5][1]);
    acc[6][0] = fmaf(a1.z, w.x, acc[6][0]); acc[6][1] = fmaf(a1.z, w.y, acc[6][1]);
    acc[7][0] = fmaf(a1.w, w.x, acc[7][0]); acc[7][1] = fmaf(a1.w, w.y, acc[7][1]);
  }

#pragma unroll
  for (int r = 0; r < 8; ++r) {
    __hip_bfloat162 p;
    p.x = __float2bfloat16(acc[r][0]);
    p.y = __float2bfloat16(acc[r][1]);
    h0b2[(size_t)(row0 + r0 + r) * 64 + lane] = *(unsigned int*)&p;
  }
}

// ---------------------------------------------------------------------------
// P1a: per-(bucket, block) histogram. LDS atomics only.
// ---------------------------------------------------------------------------
__global__ __launch_bounds__(256) void p1hist_kernel(
    const int* __restrict__ dst, int* __restrict__ histG) {
  __shared__ int lh[NB];
  const int tid = threadIdx.x;
  const int blk = blockIdx.x;
  for (int i = tid; i < NB; i += 256) lh[i] = 0;
  __syncthreads();

  const int e0 = blk * EPB;
  const int e1 = min(e0 + EPB, N_EDGES);
  for (int i = e0 + tid; i < e1; i += 256)
    atomicAdd(&lh[dst[i] >> 9], 1);
  __syncthreads();

  for (int i = tid; i < NB; i += 256)
    histG[i * NBLK + blk] = lh[i];   // bucket-major for the scan
}

// ---------------------------------------------------------------------------
// Exclusive scan of histG[HIST_M] in place (bucket-major order).
// After this, histG[b*NBLK + blk] = start cursor for (bucket b, block blk),
// and histG[b*NBLK] = start of bucket b's region.
// ---------------------------------------------------------------------------
#define SCAN_T 1024
__global__ __launch_bounds__(SCAN_T) void gscan_kernel(int* __restrict__ histG) {
  __shared__ int partials[SCAN_T];
  const int t = threadIdx.x;
  const int chunk = (HIST_M + SCAN_T - 1) / SCAN_T;   // 75
  const int lo = t * chunk;
  const int hi = min(lo + chunk, HIST_M);

  int sum = 0;
  for (int i = lo; i < hi; ++i) sum += histG[i];
  partials[t] = sum;
  __syncthreads();

  for (int off = 1; off < SCAN_T; off <<= 1) {
    int v = (t >= off) ? partials[t - off] : 0;
    __syncthreads();
    partials[t] += v;
    __syncthreads();
  }

  int run = (t > 0) ? partials[t - 1] : 0;
  for (int i = lo; i < hi; ++i) {
    const int d = histG[i];
    histG[i] = run;
    run += d;
  }
}

// ---------------------------------------------------------------------------
// P1b: scatter edges into bucket regions. Entry packs src (17b) | dst_local
// (9b) in .x, weight bits in .y. Per block per bucket the appends are
// address-contiguous (~21 entries avg) -> near line-granular writes.
// ---------------------------------------------------------------------------
__global__ __launch_bounds__(256) void p1scatter_kernel(
    const int* __restrict__ src, const int* __restrict__ dst,
    const float* __restrict__ ew, const int* __restrict__ histG,
    uint2* __restrict__ bucketed) {
  __shared__ int cur[NB];
  const int tid = threadIdx.x;
  const int blk = blockIdx.x;
  for (int i = tid; i < NB; i += 256) cur[i] = histG[i * NBLK + blk];
  __syncthreads();

  const int e0 = blk * EPB;
  const int e1 = min(e0 + EPB, N_EDGES);
  for (int i = e0 + tid; i < e1; i += 256) {
    const int d = dst[i];
    const int b = d >> 9;
    const int pos = atomicAdd(&cur[b], 1);
    bucketed[pos] = make_uint2((unsigned)src[i] | ((unsigned)(d & 511) << 17),
                               __float_as_uint(ew[i]));
  }
}

// ---------------------------------------------------------------------------
// P2: one block per bucket. Derives node-level CSR offsets (LDS hist + scan
// over the 512 nodes) AND does the final dst-sorted placement. The scatter is
// confined to the bucket's ~130 KB output window -> L2-resident, no write amp.
// ---------------------------------------------------------------------------
__global__ __launch_bounds__(256) void p2place_kernel(
    const uint2* __restrict__ bucketed, const int* __restrict__ histG,
    int* __restrict__ offsets, int2* __restrict__ srcw) {
  __shared__ int cnt[512];
  __shared__ int part[256];
  const int t = threadIdx.x;
  const int b = blockIdx.x;
  const int node0 = b << 9;
  const int beg = histG[b * NBLK];
  const int end = (b == NB - 1) ? N_EDGES : histG[(b + 1) * NBLK];

  cnt[t] = 0; cnt[t + 256] = 0;
  __syncthreads();

  for (int j = beg + t; j < end; j += 256)
    atomicAdd(&cnt[bucketed[j].x >> 17], 1);
  __syncthreads();

  const int a0 = cnt[2 * t];
  const int a1 = cnt[2 * t + 1];
  part[t] = a0 + a1;
  __syncthreads();
  for (int off = 1; off < 256; off <<= 1) {
    int v = (t >= off) ? part[t - off] : 0;
    __syncthreads();
    part[t] += v;
    __syncthreads();
  }
  const int base = (t > 0) ? part[t - 1] : 0;

  const int o0 = beg + base;
  const int o1 = o0 + a0;
  cnt[2 * t]     = o0;    // reuse as global cursors
  cnt[2 * t + 1] = o1;
  const int n0 = node0 + 2 * t;
  if (n0 < N_NODES)     offsets[n0]     = o0;
  if (n0 + 1 < N_NODES) offsets[n0 + 1] = o1;
  if (b == NB - 1 && t == 0) offsets[N_NODES] = N_EDGES;
  __syncthreads();

  for (int j = beg + t; j < end; j += 256) {
    const uint2 en = bucketed[j];
    const int slot = atomicAdd(&cnt[en.x >> 17], 1);
    srcw[slot] = make_int2((int)(en.x & 0x1FFFFu), (int)en.y);
  }
}

// ---------------------------------------------------------------------------
// Fused gather0 + bias + ReLU + GEMM1. h0 bf16x2; h1 stored bf16.
// 4x edge unroll for outstanding-load overlap (L3-latency-bound loop).
// ---------------------------------------------------------------------------
__global__ __launch_bounds__(256) void gather0_gemm1_kernel(
    const unsigned int* __restrict__ h0b2, const int2* __restrict__ srcw,
    const int* __restrict__ offsets, const float* __restrict__ b0,
    const float* __restrict__ W1, __hip_bfloat16* __restrict__ h1b) {
  __shared__ float hs[4][N_HIDDEN];
  const int wave = threadIdx.x >> 6;
  const int lane = threadIdx.x & 63;
  const int node = blockIdx.x * 4 + wave;

  const int beg = __builtin_amdgcn_readfirstlane(offsets[node]);
  const int end = __builtin_amdgcn_readfirstlane(offsets[node + 1]);
  const int f   = lane * 2;

  float ax = 0.f, ay = 0.f;
  int j = beg;
  for (; j + 4 <= end; j += 4) {
    const int2 s0 = srcw[j];
    const int2 s1 = srcw[j + 1];
    const int2 s2 = srcw[j + 2];
    const int2 s3 = srcw[j + 3];
    const unsigned int u0 = h0b2[(size_t)s0.x * 64 + lane];
    const unsigned int u1 = h0b2[(size_t)s1.x * 64 + lane];
    const unsigned int u2 = h0b2[(size_t)s2.x * 64 + lane];
    const unsigned int u3 = h0b2[(size_t)s3.x * 64 + lane];
    const float w0 = __int_as_float(s0.y);
    const float w1 = __int_as_float(s1.y);
    const float w2 = __int_as_float(s2.y);
    const float w3 = __int_as_float(s3.y);
    ax = fmaf(__uint_as_float(u0 << 16), w0, ax);
    ay = fmaf(__uint_as_float(u0 & 0xFFFF0000u), w0, ay);
    ax = fmaf(__uint_as_float(u1 << 16), w1, ax);
    ay = fmaf(__uint_as_float(u1 & 0xFFFF0000u), w1, ay);
    ax = fmaf(__uint_as_float(u2 << 16), w2, ax);
    ay = fmaf(__uint_as_float(u2 & 0xFFFF0000u), w2, ay);
    ax = fmaf(__uint_as_float(u3 << 16), w3, ax);
    ay = fmaf(__uint_as_float(u3 & 0xFFFF0000u), w3, ay);
  }
  for (; j < end; ++j) {
    const int2 s0 = srcw[j];
    const unsigned int u0 = h0b2[(size_t)s0.x * 64 + lane];
    const float w0 = __int_as_float(s0.y);
    ax = fmaf(__uint_as_float(u0 << 16), w0, ax);
    ay = fmaf(__uint_as_float(u0 & 0xFFFF0000u), w0, ay);
  }

  const float v0 = ax + b0[f];
  const float v1 = ay + b0[f + 1];
  hs[wave][f]     = v0 > 0.f ? v0 : 0.f;
  hs[wave][f + 1] = v1 > 0.f ? v1 : 0.f;
  __syncthreads();

  if (lane < OUT_FEATS) {
    float o = 0.f;
#pragma unroll 8
    for (int k = 0; k < N_HIDDEN; ++k)
      o = fmaf(hs[wave][k], W1[k * OUT_FEATS + lane], o);
    h1b[(size_t)node * OUT_FEATS + lane] = __float2bfloat16(o);
  }
}

// ---------------------------------------------------------------------------
// Fused gather1 + bias + log_softmax. h1 bf16 (halves gather traffic).
// ---------------------------------------------------------------------------
__global__ __launch_bounds__(256) void gather1_lsm_kernel(
    const unsigned short* __restrict__ h1b, const int2* __restrict__ srcw,
    const int* __restrict__ offsets, const float* __restrict__ b1,
    float* __restrict__ out) {
  const int wave = threadIdx.x >> 6;
  const int lane = threadIdx.x & 63;
  const int node = blockIdx.x * 4 + wave;

  const int beg = __builtin_amdgcn_readfirstlane(offsets[node]);
  const int end = __builtin_amdgcn_readfirstlane(offsets[node + 1]);

  float acc = 0.f;
  if (lane < OUT_FEATS) {
    int j = beg;
    for (; j + 4 <= end; j += 4) {
      const int2 s0 = srcw[j];
      const int2 s1 = srcw[j + 1];
      const int2 s2 = srcw[j + 2];
      const int2 s3 = srcw[j + 3];
      const unsigned int u0 = h1b[(size_t)s0.x * OUT_FEATS + lane];
      const unsigned int u1 = h1b[(size_t)s1.x * OUT_FEATS + lane];
      const unsigned int u2 = h1b[(size_t)s2.x * OUT_FEATS + lane];
      const unsigned int u3 = h1b[(size_t)s3.x * OUT_FEATS + lane];
      acc = fmaf(__uint_as_float(u0 << 16), __int_as_float(s0.y), acc);
      acc = fmaf(__uint_as_float(u1 << 16), __int_as_float(s1.y), acc);
      acc = fmaf(__uint_as_float(u2 << 16), __int_as_float(s2.y), acc);
      acc = fmaf(__uint_as_float(u3 << 16), __int_as_float(s3.y), acc);
    }
    for (; j < end; ++j) {
      const int2 s0 = srcw[j];
      const unsigned int u0 = h1b[(size_t)s0.x * OUT_FEATS + lane];
      acc = fmaf(__uint_as_float(u0 << 16), __int_as_float(s0.y), acc);
    }
    acc += b1[lane];
  } else {
    acc = -INFINITY;
  }

  float m = acc;
#pragma unroll
  for (int off = 32; off > 0; off >>= 1) m = fmaxf(m, __shfl_xor(m, off));

  float s = (lane < OUT_FEATS) ? expf(acc - m) : 0.f;
#pragma unroll
  for (int off = 32; off > 0; off >>= 1) s += __shfl_xor(s, off);

  if (lane < OUT_FEATS)
    out[(size_t)node * OUT_FEATS + lane] = acc - m - logf(s);
}

// ---------------------------------------------------------------------------
extern "C" void kernel_launch(void* const* d_in, const int* in_sizes, int n_in,
                              void* d_out, int out_size, void* d_ws, size_t ws_size,
                              hipStream_t stream) {
  const float* x   = (const float*)d_in[0];
  const float* W0  = (const float*)d_in[1];
  const float* b0  = (const float*)d_in[2];
  const float* W1  = (const float*)d_in[3];
  const float* b1  = (const float*)d_in[4];
  const float* ew  = (const float*)d_in[5];
  const int*   src = (const int*)d_in[6];
  const int*   dst = (const int*)d_in[7];
  float* out = (float*)d_out;

  // Workspace layout, peak ~85.5 MB (<= 102.4 MB proven available):
  //   h0b2     [0,          25,600,000)   N*64 uint (bf16x2)
  //   srcw     [25,600,000, 51,200,000)   E int2, dst-sorted (final CSR vals)
  //   bucketed [51,200,000, 76,800,000)   E uint2, bucket-partitioned
  //   offsets  [76,800,000, 77,200,064)   N+1 int
  //   histG    [77,200,064, 77,506,624)   NB*NBLK int
  //   h1b      [77,506,624, 85,506,624)   N*40 bf16
  char* ws = (char*)d_ws;
  unsigned int* h0b2 = (unsigned int*)(ws);
  int2*  srcw     = (int2*)(ws + 25600000);
  uint2* bucketed = (uint2*)(ws + 51200000);
  int*   offsets  = (int*)(ws + 76800000);
  int*   histG    = (int*)(ws + 77200064);
  __hip_bfloat16* h1b = (__hip_bfloat16*)(ws + 77506624);

  // CSR build via two-level bucket partition (no global atomics, no memset).
  p1hist_kernel<<<NBLK, 256, 0, stream>>>(dst, histG);
  gscan_kernel<<<1, SCAN_T, 0, stream>>>(histG);
  p1scatter_kernel<<<NBLK, 256, 0, stream>>>(src, dst, ew, histG, bucketed);
  p2place_kernel<<<NB, 256, 0, stream>>>(bucketed, histG, offsets, srcw);

  gemm0_kernel<<<N_NODES / 32, 256, 0, stream>>>(x, W0, h0b2);
  gather0_gemm1_kernel<<<N_NODES / 4, 256, 0, stream>>>(h0b2, srcw, offsets, b0, W1, h1b);
  gather1_lsm_kernel<<<N_NODES / 4, 256, 0, stream>>>((const unsigned short*)h1b, srcw, offsets, b1, out);
}

// Round 5
// 682.485 us; speedup vs baseline: 11.7296x; 1.1473x over previous
//
#include <hip/hip_runtime.h>
#include <hip/hip_bf16.h>
#include <cstdint>
#include <cstddef>

#define N_NODES   100000
#define N_EDGES   3200000
#define IN_FEATS  256
#define N_HIDDEN  128
#define OUT_FEATS 40

// Bucket partition: bucket = dst >> 9 (512 nodes/bucket)
#define NB        196
#define EPB       8192
#define NBLK      391
#define HIST_M    (NB * NBLK)

typedef __attribute__((ext_vector_type(8))) __bf16 bf16x8;
typedef __attribute__((ext_vector_type(4))) float f32x4;

// ---------------------------------------------------------------------------
// GEMM0 via MFMA: h0 = bf16(bf16(x) @ bf16(W0))  [N,256]x[256,128].
// Block = 256 thr = 4 waves; wave w: row-block rb=w&1 (16 rows), col-half
// ch=w>>1 (64 cols = 4 col-blocks of 16). 5 tiles of 32 rows per block.
// B-frags (W0) preloaded to registers once per block (4 cb x 8 q x 16B).
// A-frags from LDS x-tile staged bf16, row pitch 264 halfwords (pad 8 ->
// rows r,r+8 share banks = 2-way only, free).
// Verified layouts: A[m=lane&15][k=(lane>>4)*8+j]; B[k=(lane>>4)*8+j][n=lane&15];
// C col=lane&15, row=(lane>>4)*4+reg.
// ---------------------------------------------------------------------------
__global__ __launch_bounds__(256) void gemm0_mfma_kernel(
    const float* __restrict__ x, const float* __restrict__ W0,
    unsigned short* __restrict__ h0 /* bf16 [N][128] */) {
  __shared__ __align__(16) unsigned short xb[32 * 264];
  const int tid  = threadIdx.x;
  const int lane = tid & 63;
  const int wave = tid >> 6;
  const int rb   = wave & 1;
  const int ch   = wave >> 1;
  const int l15  = lane & 15;
  const int g    = lane >> 4;

  // Preload B fragments (once per block; W0 is 128KB, L2-resident).
  bf16x8 Bf[4][8];
#pragma unroll
  for (int cb = 0; cb < 4; ++cb) {
    const int col = ch * 64 + cb * 16 + l15;
#pragma unroll
    for (int q = 0; q < 8; ++q) {
      const int k0 = q * 32 + g * 8;
      uint4 uw;
      {
        __hip_bfloat162 p;
        p.x = __float2bfloat16(W0[(size_t)(k0 + 0) * N_HIDDEN + col]);
        p.y = __float2bfloat16(W0[(size_t)(k0 + 1) * N_HIDDEN + col]);
        uw.x = *(unsigned int*)&p;
        p.x = __float2bfloat16(W0[(size_t)(k0 + 2) * N_HIDDEN + col]);
        p.y = __float2bfloat16(W0[(size_t)(k0 + 3) * N_HIDDEN + col]);
        uw.y = *(unsigned int*)&p;
        p.x = __float2bfloat16(W0[(size_t)(k0 + 4) * N_HIDDEN + col]);
        p.y = __float2bfloat16(W0[(size_t)(k0 + 5) * N_HIDDEN + col]);
        uw.z = *(unsigned int*)&p;
        p.x = __float2bfloat16(W0[(size_t)(k0 + 6) * N_HIDDEN + col]);
        p.y = __float2bfloat16(W0[(size_t)(k0 + 7) * N_HIDDEN + col]);
        uw.w = *(unsigned int*)&p;
      }
      Bf[cb][q] = __builtin_bit_cast(bf16x8, uw);
    }
  }

  for (int t = 0; t < 5; ++t) {
    const int row0 = (blockIdx.x * 5 + t) * 32;
    __syncthreads();   // xb free from previous tile's readers
    // Stage x tile as bf16 (coalesced float2 reads; conflict-free writes).
    for (int i = tid; i < 32 * 128; i += 256) {
      const int row = i >> 7, kp = i & 127;
      const float2 v = *(const float2*)(x + (size_t)(row0 + row) * IN_FEATS + kp * 2);
      __hip_bfloat162 p;
      p.x = __float2bfloat16(v.x);
      p.y = __float2bfloat16(v.y);
      *(unsigned int*)&xb[row * 264 + kp * 2] = *(unsigned int*)&p;
    }
    __syncthreads();

    f32x4 acc[4];
#pragma unroll
    for (int cb = 0; cb < 4; ++cb) acc[cb] = (f32x4){0.f, 0.f, 0.f, 0.f};

#pragma unroll
    for (int q = 0; q < 8; ++q) {
      const bf16x8 a = *(const bf16x8*)&xb[(rb * 16 + l15) * 264 + q * 32 + g * 8];
      acc[0] = __builtin_amdgcn_mfma_f32_16x16x32_bf16(a, Bf[0][q], acc[0], 0, 0, 0);
      acc[1] = __builtin_amdgcn_mfma_f32_16x16x32_bf16(a, Bf[1][q], acc[1], 0, 0, 0);
      acc[2] = __builtin_amdgcn_mfma_f32_16x16x32_bf16(a, Bf[2][q], acc[2], 0, 0, 0);
      acc[3] = __builtin_amdgcn_mfma_f32_16x16x32_bf16(a, Bf[3][q], acc[3], 0, 0, 0);
    }

#pragma unroll
    for (int cb = 0; cb < 4; ++cb) {
      const int col = ch * 64 + cb * 16 + l15;
#pragma unroll
      for (int r = 0; r < 4; ++r) {
        const int row = row0 + rb * 16 + g * 4 + r;
        __hip_bfloat16 hb = __float2bfloat16(acc[cb][r]);
        h0[(size_t)row * N_HIDDEN + col] = *(unsigned short*)&hb;
      }
    }
  }
}

// ---------------------------------------------------------------------------
// CSR build (two-level bucket partition) — unchanged from R4.
// ---------------------------------------------------------------------------
__global__ __launch_bounds__(256) void p1hist_kernel(
    const int* __restrict__ dst, int* __restrict__ histG) {
  __shared__ int lh[NB];
  const int tid = threadIdx.x;
  const int blk = blockIdx.x;
  for (int i = tid; i < NB; i += 256) lh[i] = 0;
  __syncthreads();

  const int e0 = blk * EPB;
  const int e1 = min(e0 + EPB, N_EDGES);
  for (int i = e0 + tid; i < e1; i += 256)
    atomicAdd(&lh[dst[i] >> 9], 1);
  __syncthreads();

  for (int i = tid; i < NB; i += 256)
    histG[i * NBLK + blk] = lh[i];
}

#define SCAN_T 1024
__global__ __launch_bounds__(SCAN_T) void gscan_kernel(int* __restrict__ histG) {
  __shared__ int partials[SCAN_T];
  const int t = threadIdx.x;
  const int chunk = (HIST_M + SCAN_T - 1) / SCAN_T;
  const int lo = t * chunk;
  const int hi = min(lo + chunk, HIST_M);

  int sum = 0;
  for (int i = lo; i < hi; ++i) sum += histG[i];
  partials[t] = sum;
  __syncthreads();

  for (int off = 1; off < SCAN_T; off <<= 1) {
    int v = (t >= off) ? partials[t - off] : 0;
    __syncthreads();
    partials[t] += v;
    __syncthreads();
  }

  int run = (t > 0) ? partials[t - 1] : 0;
  for (int i = lo; i < hi; ++i) {
    const int d = histG[i];
    histG[i] = run;
    run += d;
  }
}

__global__ __launch_bounds__(256) void p1scatter_kernel(
    const int* __restrict__ src, const int* __restrict__ dst,
    const float* __restrict__ ew, const int* __restrict__ histG,
    uint2* __restrict__ bucketed) {
  __shared__ int cur[NB];
  const int tid = threadIdx.x;
  const int blk = blockIdx.x;
  for (int i = tid; i < NB; i += 256) cur[i] = histG[i * NBLK + blk];
  __syncthreads();

  const int e0 = blk * EPB;
  const int e1 = min(e0 + EPB, N_EDGES);
  for (int i = e0 + tid; i < e1; i += 256) {
    const int d = dst[i];
    const int b = d >> 9;
    const int pos = atomicAdd(&cur[b], 1);
    bucketed[pos] = make_uint2((unsigned)src[i] | ((unsigned)(d & 511) << 17),
                               __float_as_uint(ew[i]));
  }
}

__global__ __launch_bounds__(256) void p2place_kernel(
    const uint2* __restrict__ bucketed, const int* __restrict__ histG,
    int* __restrict__ offsets, int2* __restrict__ srcw) {
  __shared__ int cnt[512];
  __shared__ int part[256];
  const int t = threadIdx.x;
  const int b = blockIdx.x;
  const int node0 = b << 9;
  const int beg = histG[b * NBLK];
  const int end = (b == NB - 1) ? N_EDGES : histG[(b + 1) * NBLK];

  cnt[t] = 0; cnt[t + 256] = 0;
  __syncthreads();

  for (int j = beg + t; j < end; j += 256)
    atomicAdd(&cnt[bucketed[j].x >> 17], 1);
  __syncthreads();

  const int a0 = cnt[2 * t];
  const int a1 = cnt[2 * t + 1];
  part[t] = a0 + a1;
  __syncthreads();
  for (int off = 1; off < 256; off <<= 1) {
    int v = (t >= off) ? part[t - off] : 0;
    __syncthreads();
    part[t] += v;
    __syncthreads();
  }
  const int base = (t > 0) ? part[t - 1] : 0;

  const int o0 = beg + base;
  const int o1 = o0 + a0;
  cnt[2 * t]     = o0;
  cnt[2 * t + 1] = o1;
  const int n0 = node0 + 2 * t;
  if (n0 < N_NODES)     offsets[n0]     = o0;
  if (n0 + 1 < N_NODES) offsets[n0 + 1] = o1;
  if (b == NB - 1 && t == 0) offsets[N_NODES] = N_EDGES;
  __syncthreads();

  for (int j = beg + t; j < end; j += 256) {
    const uint2 en = bucketed[j];
    const int slot = atomicAdd(&cnt[en.x >> 17], 1);
    srcw[slot] = make_int2((int)(en.x & 0x1FFFFu), (int)en.y);
  }
}

// ---------------------------------------------------------------------------
// Fused gather0 + bias + ReLU + GEMM1. 8-edge batches: 8 srcw loads, then 8
// independent h0-row loads in flight (MLP 8 vs 4) — this loop is L3-latency-
// bound, not BW-bound.
// ---------------------------------------------------------------------------
__global__ __launch_bounds__(256) void gather0_gemm1_kernel(
    const unsigned int* __restrict__ h0b2, const int2* __restrict__ srcw,
    const int* __restrict__ offsets, const float* __restrict__ b0,
    const float* __restrict__ W1, __hip_bfloat16* __restrict__ h1b) {
  __shared__ float hs[4][N_HIDDEN];
  const int wave = threadIdx.x >> 6;
  const int lane = threadIdx.x & 63;
  const int node = blockIdx.x * 4 + wave;

  const int beg = __builtin_amdgcn_readfirstlane(offsets[node]);
  const int end = __builtin_amdgcn_readfirstlane(offsets[node + 1]);
  const int f   = lane * 2;

  float ax = 0.f, ay = 0.f;
  int j = beg;
  for (; j + 8 <= end; j += 8) {
    const int2 s0 = srcw[j];
    const int2 s1 = srcw[j + 1];
    const int2 s2 = srcw[j + 2];
    const int2 s3 = srcw[j + 3];
    const int2 s4 = srcw[j + 4];
    const int2 s5 = srcw[j + 5];
    const int2 s6 = srcw[j + 6];
    const int2 s7 = srcw[j + 7];
    const unsigned int u0 = h0b2[(size_t)s0.x * 64 + lane];
    const unsigned int u1 = h0b2[(size_t)s1.x * 64 + lane];
    const unsigned int u2 = h0b2[(size_t)s2.x * 64 + lane];
    const unsigned int u3 = h0b2[(size_t)s3.x * 64 + lane];
    const unsigned int u4 = h0b2[(size_t)s4.x * 64 + lane];
    const unsigned int u5 = h0b2[(size_t)s5.x * 64 + lane];
    const unsigned int u6 = h0b2[(size_t)s6.x * 64 + lane];
    const unsigned int u7 = h0b2[(size_t)s7.x * 64 + lane];
    ax = fmaf(__uint_as_float(u0 << 16),          __int_as_float(s0.y), ax);
    ay = fmaf(__uint_as_float(u0 & 0xFFFF0000u),  __int_as_float(s0.y), ay);
    ax = fmaf(__uint_as_float(u1 << 16),          __int_as_float(s1.y), ax);
    ay = fmaf(__uint_as_float(u1 & 0xFFFF0000u),  __int_as_float(s1.y), ay);
    ax = fmaf(__uint_as_float(u2 << 16),          __int_as_float(s2.y), ax);
    ay = fmaf(__uint_as_float(u2 & 0xFFFF0000u),  __int_as_float(s2.y), ay);
    ax = fmaf(__uint_as_float(u3 << 16),          __int_as_float(s3.y), ax);
    ay = fmaf(__uint_as_float(u3 & 0xFFFF0000u),  __int_as_float(s3.y), ay);
    ax = fmaf(__uint_as_float(u4 << 16),          __int_as_float(s4.y), ax);
    ay = fmaf(__uint_as_float(u4 & 0xFFFF0000u),  __int_as_float(s4.y), ay);
    ax = fmaf(__uint_as_float(u5 << 16),          __int_as_float(s5.y), ax);
    ay = fmaf(__uint_as_float(u5 & 0xFFFF0000u),  __int_as_float(s5.y), ay);
    ax = fmaf(__uint_as_float(u6 << 16),          __int_as_float(s6.y), ax);
    ay = fmaf(__uint_as_float(u6 & 0xFFFF0000u),  __int_as_float(s6.y), ay);
    ax = fmaf(__uint_as_float(u7 << 16),          __int_as_float(s7.y), ax);
    ay = fmaf(__uint_as_float(u7 & 0xFFFF0000u),  __int_as_float(s7.y), ay);
  }
  for (; j < end; ++j) {
    const int2 s0 = srcw[j];
    const unsigned int u0 = h0b2[(size_t)s0.x * 64 + lane];
    ax = fmaf(__uint_as_float(u0 << 16),         __int_as_float(s0.y), ax);
    ay = fmaf(__uint_as_float(u0 & 0xFFFF0000u), __int_as_float(s0.y), ay);
  }

  const float v0 = ax + b0[f];
  const float v1 = ay + b0[f + 1];
  hs[wave][f]     = v0 > 0.f ? v0 : 0.f;
  hs[wave][f + 1] = v1 > 0.f ? v1 : 0.f;
  __syncthreads();

  if (lane < OUT_FEATS) {
    float o = 0.f;
#pragma unroll 8
    for (int k = 0; k < N_HIDDEN; ++k)
      o = fmaf(hs[wave][k], W1[k * OUT_FEATS + lane], o);
    h1b[(size_t)node * OUT_FEATS + lane] = __float2bfloat16(o);
  }
}

// ---------------------------------------------------------------------------
// Fused gather1 + bias + log_softmax, 8-edge batches.
// ---------------------------------------------------------------------------
__global__ __launch_bounds__(256) void gather1_lsm_kernel(
    const unsigned short* __restrict__ h1b, const int2* __restrict__ srcw,
    const int* __restrict__ offsets, const float* __restrict__ b1,
    float* __restrict__ out) {
  const int wave = threadIdx.x >> 6;
  const int lane = threadIdx.x & 63;
  const int node = blockIdx.x * 4 + wave;

  const int beg = __builtin_amdgcn_readfirstlane(offsets[node]);
  const int end = __builtin_amdgcn_readfirstlane(offsets[node + 1]);

  float acc = 0.f;
  if (lane < OUT_FEATS) {
    int j = beg;
    for (; j + 8 <= end; j += 8) {
      const int2 s0 = srcw[j];
      const int2 s1 = srcw[j + 1];
      const int2 s2 = srcw[j + 2];
      const int2 s3 = srcw[j + 3];
      const int2 s4 = srcw[j + 4];
      const int2 s5 = srcw[j + 5];
      const int2 s6 = srcw[j + 6];
      const int2 s7 = srcw[j + 7];
      const unsigned int u0 = h1b[(size_t)s0.x * OUT_FEATS + lane];
      const unsigned int u1 = h1b[(size_t)s1.x * OUT_FEATS + lane];
      const unsigned int u2 = h1b[(size_t)s2.x * OUT_FEATS + lane];
      const unsigned int u3 = h1b[(size_t)s3.x * OUT_FEATS + lane];
      const unsigned int u4 = h1b[(size_t)s4.x * OUT_FEATS + lane];
      const unsigned int u5 = h1b[(size_t)s5.x * OUT_FEATS + lane];
      const unsigned int u6 = h1b[(size_t)s6.x * OUT_FEATS + lane];
      const unsigned int u7 = h1b[(size_t)s7.x * OUT_FEATS + lane];
      acc = fmaf(__uint_as_float(u0 << 16), __int_as_float(s0.y), acc);
      acc = fmaf(__uint_as_float(u1 << 16), __int_as_float(s1.y), acc);
      acc = fmaf(__uint_as_float(u2 << 16), __int_as_float(s2.y), acc);
      acc = fmaf(__uint_as_float(u3 << 16), __int_as_float(s3.y), acc);
      acc = fmaf(__uint_as_float(u4 << 16), __int_as_float(s4.y), acc);
      acc = fmaf(__uint_as_float(u5 << 16), __int_as_float(s5.y), acc);
      acc = fmaf(__uint_as_float(u6 << 16), __int_as_float(s6.y), acc);
      acc = fmaf(__uint_as_float(u7 << 16), __int_as_float(s7.y), acc);
    }
    for (; j < end; ++j) {
      const int2 s0 = srcw[j];
      const unsigned int u0 = h1b[(size_t)s0.x * OUT_FEATS + lane];
      acc = fmaf(__uint_as_float(u0 << 16), __int_as_float(s0.y), acc);
    }
    acc += b1[lane];
  } else {
    acc = -INFINITY;
  }

  float m = acc;
#pragma unroll
  for (int off = 32; off > 0; off >>= 1) m = fmaxf(m, __shfl_xor(m, off));

  float s = (lane < OUT_FEATS) ? expf(acc - m) : 0.f;
#pragma unroll
  for (int off = 32; off > 0; off >>= 1) s += __shfl_xor(s, off);

  if (lane < OUT_FEATS)
    out[(size_t)node * OUT_FEATS + lane] = acc - m - logf(s);
}

// ---------------------------------------------------------------------------
extern "C" void kernel_launch(void* const* d_in, const int* in_sizes, int n_in,
                              void* d_out, int out_size, void* d_ws, size_t ws_size,
                              hipStream_t stream) {
  const float* x   = (const float*)d_in[0];
  const float* W0  = (const float*)d_in[1];
  const float* b0  = (const float*)d_in[2];
  const float* W1  = (const float*)d_in[3];
  const float* b1  = (const float*)d_in[4];
  const float* ew  = (const float*)d_in[5];
  const int*   src = (const int*)d_in[6];
  const int*   dst = (const int*)d_in[7];
  float* out = (float*)d_out;

  // Workspace layout, peak ~85.5 MB:
  //   h0b2     [0,          25,600,000)   N*128 bf16 (= N*64 uint words)
  //   srcw     [25,600,000, 51,200,000)   E int2, dst-sorted
  //   bucketed [51,200,000, 76,800,000)   E uint2, bucket-partitioned
  //   offsets  [76,800,000, 77,200,064)   N+1 int
  //   histG    [77,200,064, 77,506,624)   NB*NBLK int
  //   h1b      [77,506,624, 85,506,624)   N*40 bf16
  char* ws = (char*)d_ws;
  unsigned int* h0b2 = (unsigned int*)(ws);
  int2*  srcw     = (int2*)(ws + 25600000);
  uint2* bucketed = (uint2*)(ws + 51200000);
  int*   offsets  = (int*)(ws + 76800000);
  int*   histG    = (int*)(ws + 77200064);
  __hip_bfloat16* h1b = (__hip_bfloat16*)(ws + 77506624);

  p1hist_kernel<<<NBLK, 256, 0, stream>>>(dst, histG);
  gscan_kernel<<<1, SCAN_T, 0, stream>>>(histG);
  p1scatter_kernel<<<NBLK, 256, 0, stream>>>(src, dst, ew, histG, bucketed);
  p2place_kernel<<<NB, 256, 0, stream>>>(bucketed, histG, offsets, srcw);

  gemm0_mfma_kernel<<<625, 256, 0, stream>>>(x, W0, (unsigned short*)h0b2);
  gather0_gemm1_kernel<<<N_NODES / 4, 256, 0, stream>>>(h0b2, srcw, offsets, b0, W1, h1b);
  gather1_lsm_kernel<<<N_NODES / 4, 256, 0, stream>>>((const unsigned short*)h1b, srcw, offsets, b1, out);
}

// Round 6
// 674.735 us; speedup vs baseline: 11.8643x; 1.0115x over previous
//
#include <hip/hip_runtime.h>
#include <hip/hip_bf16.h>
#include <cstdint>
#include <cstddef>

#define N_NODES   100000
#define N_EDGES   3200000
#define IN_FEATS  256
#define N_HIDDEN  128
#define OUT_FEATS 40
#define H1_PITCH  64       // h1 row padded to 64 bf16 = 128 B (2 aligned lines)

// Bucket partition: bucket = dst >> 9 (512 nodes/bucket)
#define NB        196
#define EPB       8192
#define NBLK      391
#define HIST_M    (NB * NBLK)

typedef __attribute__((ext_vector_type(8))) __bf16 bf16x8;
typedef __attribute__((ext_vector_type(4))) float f32x4;

// ---------------------------------------------------------------------------
// GEMM0 block body (MFMA): h0 = bf16(bf16(x) @ bf16(W0)), 32 rows x 128 cols
// per block, 5 tiles/block. Called from the combo kernel below.
// ---------------------------------------------------------------------------
__device__ __forceinline__ void gemm0_block(
    int bid, const float* __restrict__ x, const float* __restrict__ W0,
    unsigned short* __restrict__ h0) {
  __shared__ __align__(16) unsigned short xb[32 * 264];
  const int tid  = threadIdx.x;
  const int lane = tid & 63;
  const int wave = tid >> 6;
  const int rb   = wave & 1;
  const int ch   = wave >> 1;
  const int l15  = lane & 15;
  const int g    = lane >> 4;

  bf16x8 Bf[4][8];
#pragma unroll
  for (int cb = 0; cb < 4; ++cb) {
    const int col = ch * 64 + cb * 16 + l15;
#pragma unroll
    for (int q = 0; q < 8; ++q) {
      const int k0 = q * 32 + g * 8;
      uint4 uw;
      {
        __hip_bfloat162 p;
        p.x = __float2bfloat16(W0[(size_t)(k0 + 0) * N_HIDDEN + col]);
        p.y = __float2bfloat16(W0[(size_t)(k0 + 1) * N_HIDDEN + col]);
        uw.x = *(unsigned int*)&p;
        p.x = __float2bfloat16(W0[(size_t)(k0 + 2) * N_HIDDEN + col]);
        p.y = __float2bfloat16(W0[(size_t)(k0 + 3) * N_HIDDEN + col]);
        uw.y = *(unsigned int*)&p;
        p.x = __float2bfloat16(W0[(size_t)(k0 + 4) * N_HIDDEN + col]);
        p.y = __float2bfloat16(W0[(size_t)(k0 + 5) * N_HIDDEN + col]);
        uw.z = *(unsigned int*)&p;
        p.x = __float2bfloat16(W0[(size_t)(k0 + 6) * N_HIDDEN + col]);
        p.y = __float2bfloat16(W0[(size_t)(k0 + 7) * N_HIDDEN + col]);
        uw.w = *(unsigned int*)&p;
      }
      Bf[cb][q] = __builtin_bit_cast(bf16x8, uw);
    }
  }

  for (int t = 0; t < 5; ++t) {
    const int row0 = (bid * 5 + t) * 32;
    __syncthreads();
    for (int i = tid; i < 32 * 128; i += 256) {
      const int row = i >> 7, kp = i & 127;
      const float2 v = *(const float2*)(x + (size_t)(row0 + row) * IN_FEATS + kp * 2);
      __hip_bfloat162 p;
      p.x = __float2bfloat16(v.x);
      p.y = __float2bfloat16(v.y);
      *(unsigned int*)&xb[row * 264 + kp * 2] = *(unsigned int*)&p;
    }
    __syncthreads();

    f32x4 acc[4];
#pragma unroll
    for (int cb = 0; cb < 4; ++cb) acc[cb] = (f32x4){0.f, 0.f, 0.f, 0.f};

#pragma unroll
    for (int q = 0; q < 8; ++q) {
      const bf16x8 a = *(const bf16x8*)&xb[(rb * 16 + l15) * 264 + q * 32 + g * 8];
      acc[0] = __builtin_amdgcn_mfma_f32_16x16x32_bf16(a, Bf[0][q], acc[0], 0, 0, 0);
      acc[1] = __builtin_amdgcn_mfma_f32_16x16x32_bf16(a, Bf[1][q], acc[1], 0, 0, 0);
      acc[2] = __builtin_amdgcn_mfma_f32_16x16x32_bf16(a, Bf[2][q], acc[2], 0, 0, 0);
      acc[3] = __builtin_amdgcn_mfma_f32_16x16x32_bf16(a, Bf[3][q], acc[3], 0, 0, 0);
    }

#pragma unroll
    for (int cb = 0; cb < 4; ++cb) {
      const int col = ch * 64 + cb * 16 + l15;
#pragma unroll
      for (int r = 0; r < 4; ++r) {
        const int row = row0 + rb * 16 + g * 4 + r;
        __hip_bfloat16 hb = __float2bfloat16(acc[cb][r]);
        h0[(size_t)row * N_HIDDEN + col] = *(unsigned short*)&hb;
      }
    }
  }
}

// ---------------------------------------------------------------------------
// 256-thread exclusive scan of histG (block 0 of the combo dispatch).
// ---------------------------------------------------------------------------
__device__ __forceinline__ void gscan256_block(int* __restrict__ histG) {
  __shared__ int partials[256];
  const int t = threadIdx.x;
  const int chunk = (HIST_M + 255) / 256;   // 300
  const int lo = t * chunk;
  const int hi = min(lo + chunk, HIST_M);

  int sum = 0;
  for (int i = lo; i < hi; ++i) sum += histG[i];
  partials[t] = sum;
  __syncthreads();

  for (int off = 1; off < 256; off <<= 1) {
    int v = (t >= off) ? partials[t - off] : 0;
    __syncthreads();
    partials[t] += v;
    __syncthreads();
  }

  int run = (t > 0) ? partials[t - 1] : 0;
  for (int i = lo; i < hi; ++i) {
    const int d = histG[i];
    histG[i] = run;
    run += d;
  }
}

// Combo: block 0 runs the scan (1-block serialization hidden under gemm work),
// blocks 1..625 run gemm0. gemm0 depends only on x/W0; scan only on histG.
__global__ __launch_bounds__(256) void gscan_gemm0_kernel(
    int* __restrict__ histG, const float* __restrict__ x,
    const float* __restrict__ W0, unsigned short* __restrict__ h0) {
  if (blockIdx.x == 0) gscan256_block(histG);
  else                 gemm0_block(blockIdx.x - 1, x, W0, h0);
}

// ---------------------------------------------------------------------------
// CSR build: p1hist -> (gscan in combo) -> p1scatter -> p2place.
// ---------------------------------------------------------------------------
__global__ __launch_bounds__(256) void p1hist_kernel(
    const int* __restrict__ dst, int* __restrict__ histG) {
  __shared__ int lh[NB];
  const int tid = threadIdx.x;
  const int blk = blockIdx.x;
  for (int i = tid; i < NB; i += 256) lh[i] = 0;
  __syncthreads();

  const int e0 = blk * EPB;
  const int e1 = min(e0 + EPB, N_EDGES);
  for (int i = e0 + tid; i < e1; i += 256)
    atomicAdd(&lh[dst[i] >> 9], 1);
  __syncthreads();

  for (int i = tid; i < NB; i += 256)
    histG[i * NBLK + blk] = lh[i];
}

__global__ __launch_bounds__(256) void p1scatter_kernel(
    const int* __restrict__ src, const int* __restrict__ dst,
    const float* __restrict__ ew, const int* __restrict__ histG,
    uint2* __restrict__ bucketed) {
  __shared__ int cur[NB];
  const int tid = threadIdx.x;
  const int blk = blockIdx.x;
  for (int i = tid; i < NB; i += 256) cur[i] = histG[i * NBLK + blk];
  __syncthreads();

  const int e0 = blk * EPB;
  const int e1 = min(e0 + EPB, N_EDGES);
  for (int i = e0 + tid; i < e1; i += 256) {
    const int d = dst[i];
    const int b = d >> 9;
    const int pos = atomicAdd(&cur[b], 1);
    bucketed[pos] = make_uint2((unsigned)src[i] | ((unsigned)(d & 511) << 17),
                               __float_as_uint(ew[i]));
  }
}

__global__ __launch_bounds__(256) void p2place_kernel(
    const uint2* __restrict__ bucketed, const int* __restrict__ histG,
    int* __restrict__ offsets, int2* __restrict__ srcw) {
  __shared__ int cnt[512];
  __shared__ int part[256];
  const int t = threadIdx.x;
  const int b = blockIdx.x;
  const int node0 = b << 9;
  const int beg = histG[b * NBLK];
  const int end = (b == NB - 1) ? N_EDGES : histG[(b + 1) * NBLK];

  cnt[t] = 0; cnt[t + 256] = 0;
  __syncthreads();

  for (int j = beg + t; j < end; j += 256)
    atomicAdd(&cnt[bucketed[j].x >> 17], 1);
  __syncthreads();

  const int a0 = cnt[2 * t];
  const int a1 = cnt[2 * t + 1];
  part[t] = a0 + a1;
  __syncthreads();
  for (int off = 1; off < 256; off <<= 1) {
    int v = (t >= off) ? part[t - off] : 0;
    __syncthreads();
    part[t] += v;
    __syncthreads();
  }
  const int base = (t > 0) ? part[t - 1] : 0;

  const int o0 = beg + base;
  const int o1 = o0 + a0;
  cnt[2 * t]     = o0;
  cnt[2 * t + 1] = o1;
  const int n0 = node0 + 2 * t;
  if (n0 < N_NODES)     offsets[n0]     = o0;
  if (n0 + 1 < N_NODES) offsets[n0 + 1] = o1;
  if (b == NB - 1 && t == 0) offsets[N_NODES] = N_EDGES;
  __syncthreads();

  for (int j = beg + t; j < end; j += 256) {
    const uint2 en = bucketed[j];
    const int slot = atomicAdd(&cnt[en.x >> 17], 1);
    srcw[slot] = make_int2((int)(en.x & 0x1FFFFu), (int)en.y);
  }
}

// ---------------------------------------------------------------------------
// Fused gather0 + bias + ReLU + GEMM1 (8-edge MLP batches). h1 written at
// pitch 64 with zero pad (full 128B-line writes, no RMW).
// ---------------------------------------------------------------------------
__global__ __launch_bounds__(256) void gather0_gemm1_kernel(
    const unsigned int* __restrict__ h0b2, const int2* __restrict__ srcw,
    const int* __restrict__ offsets, const float* __restrict__ b0,
    const float* __restrict__ W1, unsigned short* __restrict__ h1b) {
  __shared__ float hs[4][N_HIDDEN];
  const int wave = threadIdx.x >> 6;
  const int lane = threadIdx.x & 63;
  const int node = blockIdx.x * 4 + wave;

  const int beg = __builtin_amdgcn_readfirstlane(offsets[node]);
  const int end = __builtin_amdgcn_readfirstlane(offsets[node + 1]);
  const int f   = lane * 2;

  float ax = 0.f, ay = 0.f;
  int j = beg;
  for (; j + 8 <= end; j += 8) {
    const int2 s0 = srcw[j];
    const int2 s1 = srcw[j + 1];
    const int2 s2 = srcw[j + 2];
    const int2 s3 = srcw[j + 3];
    const int2 s4 = srcw[j + 4];
    const int2 s5 = srcw[j + 5];
    const int2 s6 = srcw[j + 6];
    const int2 s7 = srcw[j + 7];
    const unsigned int u0 = h0b2[(size_t)s0.x * 64 + lane];
    const unsigned int u1 = h0b2[(size_t)s1.x * 64 + lane];
    const unsigned int u2 = h0b2[(size_t)s2.x * 64 + lane];
    const unsigned int u3 = h0b2[(size_t)s3.x * 64 + lane];
    const unsigned int u4 = h0b2[(size_t)s4.x * 64 + lane];
    const unsigned int u5 = h0b2[(size_t)s5.x * 64 + lane];
    const unsigned int u6 = h0b2[(size_t)s6.x * 64 + lane];
    const unsigned int u7 = h0b2[(size_t)s7.x * 64 + lane];
    ax = fmaf(__uint_as_float(u0 << 16),          __int_as_float(s0.y), ax);
    ay = fmaf(__uint_as_float(u0 & 0xFFFF0000u),  __int_as_float(s0.y), ay);
    ax = fmaf(__uint_as_float(u1 << 16),          __int_as_float(s1.y), ax);
    ay = fmaf(__uint_as_float(u1 & 0xFFFF0000u),  __int_as_float(s1.y), ay);
    ax = fmaf(__uint_as_float(u2 << 16),          __int_as_float(s2.y), ax);
    ay = fmaf(__uint_as_float(u2 & 0xFFFF0000u),  __int_as_float(s2.y), ay);
    ax = fmaf(__uint_as_float(u3 << 16),          __int_as_float(s3.y), ax);
    ay = fmaf(__uint_as_float(u3 & 0xFFFF0000u),  __int_as_float(s3.y), ay);
    ax = fmaf(__uint_as_float(u4 << 16),          __int_as_float(s4.y), ax);
    ay = fmaf(__uint_as_float(u4 & 0xFFFF0000u),  __int_as_float(s4.y), ay);
    ax = fmaf(__uint_as_float(u5 << 16),          __int_as_float(s5.y), ax);
    ay = fmaf(__uint_as_float(u5 & 0xFFFF0000u),  __int_as_float(s5.y), ay);
    ax = fmaf(__uint_as_float(u6 << 16),          __int_as_float(s6.y), ax);
    ay = fmaf(__uint_as_float(u6 & 0xFFFF0000u),  __int_as_float(s6.y), ay);
    ax = fmaf(__uint_as_float(u7 << 16),          __int_as_float(s7.y), ax);
    ay = fmaf(__uint_as_float(u7 & 0xFFFF0000u),  __int_as_float(s7.y), ay);
  }
  for (; j < end; ++j) {
    const int2 s0 = srcw[j];
    const unsigned int u0 = h0b2[(size_t)s0.x * 64 + lane];
    ax = fmaf(__uint_as_float(u0 << 16),         __int_as_float(s0.y), ax);
    ay = fmaf(__uint_as_float(u0 & 0xFFFF0000u), __int_as_float(s0.y), ay);
  }

  const float v0 = ax + b0[f];
  const float v1 = ay + b0[f + 1];
  hs[wave][f]     = v0 > 0.f ? v0 : 0.f;
  hs[wave][f + 1] = v1 > 0.f ? v1 : 0.f;
  __syncthreads();

  unsigned short w16 = 0;
  if (lane < OUT_FEATS) {
    float o = 0.f;
#pragma unroll 8
    for (int k = 0; k < N_HIDDEN; ++k)
      o = fmaf(hs[wave][k], W1[k * OUT_FEATS + lane], o);
    __hip_bfloat16 hb = __float2bfloat16(o);
    w16 = *(unsigned short*)&hb;
  }
  h1b[(size_t)node * H1_PITCH + lane] = w16;   // pad lanes write 0: full lines
}

// ---------------------------------------------------------------------------
// Fused gather1 + bias + log_softmax. h1 rows 128B-aligned (exactly 2 lines).
// ---------------------------------------------------------------------------
__global__ __launch_bounds__(256) void gather1_lsm_kernel(
    const unsigned short* __restrict__ h1b, const int2* __restrict__ srcw,
    const int* __restrict__ offsets, const float* __restrict__ b1,
    float* __restrict__ out) {
  const int wave = threadIdx.x >> 6;
  const int lane = threadIdx.x & 63;
  const int node = blockIdx.x * 4 + wave;

  const int beg = __builtin_amdgcn_readfirstlane(offsets[node]);
  const int end = __builtin_amdgcn_readfirstlane(offsets[node + 1]);

  float acc = 0.f;
  if (lane < OUT_FEATS) {
    int j = beg;
    for (; j + 8 <= end; j += 8) {
      const int2 s0 = srcw[j];
      const int2 s1 = srcw[j + 1];
      const int2 s2 = srcw[j + 2];
      const int2 s3 = srcw[j + 3];
      const int2 s4 = srcw[j + 4];
      const int2 s5 = srcw[j + 5];
      const int2 s6 = srcw[j + 6];
      const int2 s7 = srcw[j + 7];
      const unsigned int u0 = h1b[(size_t)s0.x * H1_PITCH + lane];
      const unsigned int u1 = h1b[(size_t)s1.x * H1_PITCH + lane];
      const unsigned int u2 = h1b[(size_t)s2.x * H1_PITCH + lane];
      const unsigned int u3 = h1b[(size_t)s3.x * H1_PITCH + lane];
      const unsigned int u4 = h1b[(size_t)s4.x * H1_PITCH + lane];
      const unsigned int u5 = h1b[(size_t)s5.x * H1_PITCH + lane];
      const unsigned int u6 = h1b[(size_t)s6.x * H1_PITCH + lane];
      const unsigned int u7 = h1b[(size_t)s7.x * H1_PITCH + lane];
      acc = fmaf(__uint_as_float(u0 << 16), __int_as_float(s0.y), acc);
      acc = fmaf(__uint_as_float(u1 << 16), __int_as_float(s1.y), acc);
      acc = fmaf(__uint_as_float(u2 << 16), __int_as_float(s2.y), acc);
      acc = fmaf(__uint_as_float(u3 << 16), __int_as_float(s3.y), acc);
      acc = fmaf(__uint_as_float(u4 << 16), __int_as_float(s4.y), acc);
      acc = fmaf(__uint_as_float(u5 << 16), __int_as_float(s5.y), acc);
      acc = fmaf(__uint_as_float(u6 << 16), __int_as_float(s6.y), acc);
      acc = fmaf(__uint_as_float(u7 << 16), __int_as_float(s7.y), acc);
    }
    for (; j < end; ++j) {
      const int2 s0 = srcw[j];
      const unsigned int u0 = h1b[(size_t)s0.x * H1_PITCH + lane];
      acc = fmaf(__uint_as_float(u0 << 16), __int_as_float(s0.y), acc);
    }
    acc += b1[lane];
  } else {
    acc = -INFINITY;
  }

  float m = acc;
#pragma unroll
  for (int off = 32; off > 0; off >>= 1) m = fmaxf(m, __shfl_xor(m, off));

  float s = (lane < OUT_FEATS) ? expf(acc - m) : 0.f;
#pragma unroll
  for (int off = 32; off > 0; off >>= 1) s += __shfl_xor(s, off);

  if (lane < OUT_FEATS)
    out[(size_t)node * OUT_FEATS + lane] = acc - m - logf(s);
}

// ---------------------------------------------------------------------------
extern "C" void kernel_launch(void* const* d_in, const int* in_sizes, int n_in,
                              void* d_out, int out_size, void* d_ws, size_t ws_size,
                              hipStream_t stream) {
  const float* x   = (const float*)d_in[0];
  const float* W0  = (const float*)d_in[1];
  const float* b0  = (const float*)d_in[2];
  const float* W1  = (const float*)d_in[3];
  const float* b1  = (const float*)d_in[4];
  const float* ew  = (const float*)d_in[5];
  const int*   src = (const int*)d_in[6];
  const int*   dst = (const int*)d_in[7];
  float* out = (float*)d_out;

  // Workspace layout, peak ~90.3 MB (ws >= 102.4 MB proven in R1):
  //   h0b2     [0,          25,600,000)   N*128 bf16
  //   srcw     [25,600,000, 51,200,000)   E int2, dst-sorted
  //   bucketed [51,200,000, 76,800,000)   E uint2, bucket-partitioned
  //   offsets  [76,800,000, 77,200,064)   N+1 int
  //   histG    [77,200,064, 77,506,624)   NB*NBLK int
  //   h1b      [77,506,624, 90,306,624)   N*64 bf16 (pitch-64, 128B rows)
  char* ws = (char*)d_ws;
  unsigned int* h0b2 = (unsigned int*)(ws);
  int2*  srcw     = (int2*)(ws + 25600000);
  uint2* bucketed = (uint2*)(ws + 51200000);
  int*   offsets  = (int*)(ws + 76800000);
  int*   histG    = (int*)(ws + 77200064);
  unsigned short* h1b = (unsigned short*)(ws + 77506624);

  p1hist_kernel<<<NBLK, 256, 0, stream>>>(dst, histG);
  // gscan (block 0) hidden under gemm0 (blocks 1..625) in one dispatch.
  gscan_gemm0_kernel<<<626, 256, 0, stream>>>(histG, x, W0, (unsigned short*)h0b2);
  p1scatter_kernel<<<NBLK, 256, 0, stream>>>(src, dst, ew, histG, bucketed);
  p2place_kernel<<<NB, 256, 0, stream>>>(bucketed, histG, offsets, srcw);

  gather0_gemm1_kernel<<<N_NODES / 4, 256, 0, stream>>>(h0b2, srcw, offsets, b0, W1, h1b);
  gather1_lsm_kernel<<<N_NODES / 4, 256, 0, stream>>>(h1b, srcw, offsets, b1, out);
}